// Round 1
// baseline (949.074 us; speedup 1.0000x reference)
//
#include <hip/hip_runtime.h>
#include <math.h>

// Problem constants
#define Cc    192
#define NH    8
#define HD    24
#define Sdim  7
#define Him   112
#define Wim   112
#define HW    12544      // 112*112
#define Lr    784        // tokens per stripe window (7*112)
#define NSTR  16         // stripes per branch (112/7)
#define SCALE 0.20412414523193154f  // 24^-0.5

// ---------------------------------------------------------------------------
// GEMM: Y[M][12544] = W[M][K] @ X[K][12544] + bias[M]
// BM=64, BN=64, BK=32, 256 threads, 4x4 per thread. M,K multiples of 64/32.
// ---------------------------------------------------------------------------
__global__ __launch_bounds__(256) void gemm_bias(
    const float* __restrict__ Wm, const float* __restrict__ bias,
    const float* __restrict__ X, float* __restrict__ Y, const int K) {
  __shared__ float As[32][68];   // [k][m], padded to keep 16B align + spread banks
  __shared__ float Bs[32][64];   // [k][n]
  const int tid = threadIdx.x;
  const int tx = tid & 15, ty = tid >> 4;
  const int bx = blockIdx.x, by = blockIdx.y;
  const int ca = tid & 7, ra = tid >> 3;      // A-staging: 8 float4 per 64-row
  const int cb = tid & 15, rb = tid >> 4;     // B-staging

  float acc[4][4];
#pragma unroll
  for (int i = 0; i < 4; ++i)
#pragma unroll
    for (int j = 0; j < 4; ++j) acc[i][j] = 0.f;

  for (int kk = 0; kk < K; kk += 32) {
    __syncthreads();
#pragma unroll
    for (int p = 0; p < 2; ++p) {
      const int row = ra + p * 32;
      const float4 av = *(const float4*)&Wm[(by * 64 + row) * K + kk + ca * 4];
      As[ca * 4 + 0][row] = av.x;
      As[ca * 4 + 1][row] = av.y;
      As[ca * 4 + 2][row] = av.z;
      As[ca * 4 + 3][row] = av.w;
    }
#pragma unroll
    for (int p = 0; p < 2; ++p) {
      const int row = rb + p * 16;
      *(float4*)&Bs[row][cb * 4] =
          *(const float4*)&X[(kk + row) * HW + bx * 64 + cb * 4];
    }
    __syncthreads();
#pragma unroll
    for (int k = 0; k < 32; ++k) {
      const float4 a = *(const float4*)&As[k][ty * 4];
      const float4 b = *(const float4*)&Bs[k][tx * 4];
      acc[0][0] = fmaf(a.x, b.x, acc[0][0]);
      acc[0][1] = fmaf(a.x, b.y, acc[0][1]);
      acc[0][2] = fmaf(a.x, b.z, acc[0][2]);
      acc[0][3] = fmaf(a.x, b.w, acc[0][3]);
      acc[1][0] = fmaf(a.y, b.x, acc[1][0]);
      acc[1][1] = fmaf(a.y, b.y, acc[1][1]);
      acc[1][2] = fmaf(a.y, b.z, acc[1][2]);
      acc[1][3] = fmaf(a.y, b.w, acc[1][3]);
      acc[2][0] = fmaf(a.z, b.x, acc[2][0]);
      acc[2][1] = fmaf(a.z, b.y, acc[2][1]);
      acc[2][2] = fmaf(a.z, b.z, acc[2][2]);
      acc[2][3] = fmaf(a.z, b.w, acc[2][3]);
      acc[3][0] = fmaf(a.w, b.x, acc[3][0]);
      acc[3][1] = fmaf(a.w, b.y, acc[3][1]);
      acc[3][2] = fmaf(a.w, b.z, acc[3][2]);
      acc[3][3] = fmaf(a.w, b.w, acc[3][3]);
    }
  }
#pragma unroll
  for (int i = 0; i < 4; ++i) {
    const float bi = bias[by * 64 + ty * 4 + i];
    float4 o;
    o.x = acc[i][0] + bi;
    o.y = acc[i][1] + bi;
    o.z = acc[i][2] + bi;
    o.w = acc[i][3] + bi;
    *(float4*)&Y[(by * 64 + ty * 4 + i) * HW + bx * 64 + tx * 4] = o;
  }
}

// ---------------------------------------------------------------------------
// CSWin stripe attention, one (stripe, head, row-half) per block.
// branch 0 = horizontal (token l -> pixel r*784 + l; bias by row offset l/112)
// branch 1 = vertical   (token l = h*7+s -> pixel h*112 + r*7 + s; bias by s=l%7)
// 256 threads; threads 0..195 each own 2 query rows; K/V staged in 196-key
// chunks in LDS; online softmax with deferred rescale.
// ---------------------------------------------------------------------------
__global__ __launch_bounds__(256) void attn_kernel(
    const float* __restrict__ qkv, const float* __restrict__ table,
    float* __restrict__ out, const int branch) {
  const int r = blockIdx.x, head = blockIdx.y, z = blockIdx.z;
  const int tid = threadIdx.x;
  __shared__ float Ks[196][24];
  __shared__ float Vs[196][24];

  const bool active = tid < 196;
  const int l0 = z * 392 + tid * 2;
  const int l1 = l0 + 1;
  float q0[24], q1[24], a0[24], a1[24];
  float brow0[7], brow1[7];
  float m0 = -1e30f, m1 = -1e30f, den0 = 0.f, den1 = 0.f;
  int pix0 = 0, pix1 = 0;

  if (active) {
    pix0 = branch ? (l0 / 7) * Wim + r * 7 + (l0 % 7) : r * Lr + l0;
    pix1 = branch ? (l1 / 7) * Wim + r * 7 + (l1 % 7) : r * Lr + l1;
#pragma unroll
    for (int d = 0; d < 24; ++d) {
      q0[d] = qkv[(head * 24 + d) * HW + pix0] * SCALE;
      q1[d] = qkv[(head * 24 + d) * HW + pix1] * SCALE;
      a0[d] = 0.f;
      a1[d] = 0.f;
    }
    const int sl0 = branch ? (l0 % 7) : (l0 / Wim);
    const int sl1 = branch ? (l1 % 7) : (l1 / Wim);
#pragma unroll
    for (int j = 0; j < 7; ++j) {
      brow0[j] = branch ? table[(6 * 13 + (sl0 - j + 6)) * 8 + head]
                        : table[((sl0 - j + 6) * 13 + 6) * 8 + head];
      brow1[j] = branch ? table[(6 * 13 + (sl1 - j + 6)) * 8 + head]
                        : table[((sl1 - j + 6) * 13 + 6) * 8 + head];
    }
  }

  for (int kc = 0; kc < 4; ++kc) {
    __syncthreads();  // protect LDS from previous chunk's readers
    for (int idx = tid; idx < 196 * 24; idx += 256) {
      const int d = idx / 196, m = idx - d * 196;
      const int mg = kc * 196 + m;
      const int pix = branch ? (mg / 7) * Wim + r * 7 + (mg % 7) : r * Lr + mg;
      Ks[m][d] = qkv[(Cc + head * 24 + d) * HW + pix];
      Vs[m][d] = qkv[(2 * Cc + head * 24 + d) * HW + pix];
    }
    __syncthreads();
    if (active) {
      for (int m = 0; m < 196; ++m) {
        const int mg = kc * 196 + m;
        const int sm = branch ? (mg % 7) : (mg / Wim);
        float s0 = brow0[sm], s1 = brow1[sm];
#pragma unroll
        for (int d = 0; d < 24; ++d) {
          const float kv = Ks[m][d];
          s0 = fmaf(q0[d], kv, s0);
          s1 = fmaf(q1[d], kv, s1);
        }
        if (s0 > m0) {  // deferred rescale (rare after warm-up)
          const float cf = __expf(m0 - s0);
          m0 = s0;
          den0 *= cf;
#pragma unroll
          for (int d = 0; d < 24; ++d) a0[d] *= cf;
        }
        if (s1 > m1) {
          const float cf = __expf(m1 - s1);
          m1 = s1;
          den1 *= cf;
#pragma unroll
          for (int d = 0; d < 24; ++d) a1[d] *= cf;
        }
        const float p0 = __expf(s0 - m0);
        const float p1 = __expf(s1 - m1);
        den0 += p0;
        den1 += p1;
#pragma unroll
        for (int d = 0; d < 24; ++d) {
          const float vv = Vs[m][d];
          a0[d] = fmaf(p0, vv, a0[d]);
          a1[d] = fmaf(p1, vv, a1[d]);
        }
      }
    }
  }

  if (active) {
    const float inv0 = 1.f / den0, inv1 = 1.f / den1;
#pragma unroll
    for (int d = 0; d < 24; ++d) {
      out[(head * 24 + d) * HW + pix0] = a0[d] * inv0;
      out[(head * 24 + d) * HW + pix1] = a1[d] * inv1;
    }
  }
}

// ---------------------------------------------------------------------------
// LePE (depthwise 3x3 + bias -> exact GELU -> residual) for both branches,
// then t = 0.5*(lepe_h + lepe_v)
// ---------------------------------------------------------------------------
__device__ __forceinline__ float gelu_exact(float x) {
  return 0.5f * x * (1.f + erff(x * 0.7071067811865476f));
}

__global__ __launch_bounds__(256) void lepe_combine(
    const float* __restrict__ oh, const float* __restrict__ ov,
    const float* __restrict__ wh, const float* __restrict__ bh,
    const float* __restrict__ wv, const float* __restrict__ bv,
    float* __restrict__ t) {
  const int idx = blockIdx.x * 256 + threadIdx.x;
  if (idx >= Cc * HW) return;
  const int c = idx / HW, pos = idx - c * HW;
  const int h = pos / Wim, w = pos - (pos / Wim) * Wim;
  float sh = 0.f, sv = 0.f;
#pragma unroll
  for (int ky = 0; ky < 3; ++ky) {
    const int hh = h + ky - 1;
    if (hh < 0 || hh >= Him) continue;
#pragma unroll
    for (int kx = 0; kx < 3; ++kx) {
      const int wwp = w + kx - 1;
      if (wwp < 0 || wwp >= Wim) continue;
      const int p = c * HW + hh * Wim + wwp;
      const float wt_h = wh[c * 9 + ky * 3 + kx];
      const float wt_v = wv[c * 9 + ky * 3 + kx];
      sh = fmaf(oh[p], wt_h, sh);
      sv = fmaf(ov[p], wt_v, sv);
    }
  }
  const float rh = oh[idx] + gelu_exact(sh + bh[c]);
  const float rv = ov[idx] + gelu_exact(sv + bv[c]);
  t[idx] = 0.5f * (rh + rv);
}

// ---------------------------------------------------------------------------
// Launch: qkv_h GEMM -> attn_h -> qkv_v GEMM (reuse buffer) -> attn_v
//         -> lepe+combine -> proj GEMM.
// Workspace: qkv (576*HW) + out_h + out_v + t (192*HW each) = 57.8 MB floats.
// ---------------------------------------------------------------------------
extern "C" void kernel_launch(void* const* d_in, const int* in_sizes, int n_in,
                              void* d_out, int out_size, void* d_ws,
                              size_t ws_size, hipStream_t stream) {
  const float* x        = (const float*)d_in[0];
  const float* qkv_h_w  = (const float*)d_in[1];
  const float* qkv_h_b  = (const float*)d_in[2];
  const float* qkv_v_w  = (const float*)d_in[3];
  const float* qkv_v_b  = (const float*)d_in[4];
  const float* proj_w   = (const float*)d_in[5];
  const float* proj_b   = (const float*)d_in[6];
  const float* lepe_h_w = (const float*)d_in[7];
  const float* lepe_h_b = (const float*)d_in[8];
  const float* lepe_v_w = (const float*)d_in[9];
  const float* lepe_v_b = (const float*)d_in[10];
  const float* table_h  = (const float*)d_in[11];
  const float* table_v  = (const float*)d_in[12];
  float* outp = (float*)d_out;

  float* ws    = (float*)d_ws;
  float* qkvb  = ws;                       // 576*HW floats
  float* out_h = qkvb + 3 * Cc * HW;       // 192*HW
  float* out_v = out_h + Cc * HW;          // 192*HW
  float* tbuf  = out_v + Cc * HW;          // 192*HW

  const dim3 blk(256);
  // horizontal branch
  gemm_bias<<<dim3(HW / 64, (3 * Cc) / 64), blk, 0, stream>>>(qkv_h_w, qkv_h_b,
                                                              x, qkvb, Cc);
  attn_kernel<<<dim3(NSTR, NH, 2), blk, 0, stream>>>(qkvb, table_h, out_h, 0);
  // vertical branch (reuses qkv buffer)
  gemm_bias<<<dim3(HW / 64, (3 * Cc) / 64), blk, 0, stream>>>(qkv_v_w, qkv_v_b,
                                                              x, qkvb, Cc);
  attn_kernel<<<dim3(NSTR, NH, 2), blk, 0, stream>>>(qkvb, table_v, out_v, 1);
  // lepe + combine
  lepe_combine<<<dim3((Cc * HW + 255) / 256), blk, 0, stream>>>(
      out_h, out_v, lepe_h_w, lepe_h_b, lepe_v_w, lepe_v_b, tbuf);
  // projection
  gemm_bias<<<dim3(HW / 64, Cc / 64), blk, 0, stream>>>(proj_w, proj_b, tbuf,
                                                        outp, Cc);
}

// Round 2
// 682.007 us; speedup vs baseline: 1.3916x; 1.3916x over previous
//
#include <hip/hip_runtime.h>
#include <math.h>

// Problem constants
#define Cc    192
#define NH    8
#define HD    24
#define Sdim  7
#define Him   112
#define Wim   112
#define HW    12544      // 112*112
#define Lr    784        // tokens per stripe window (7*112)
#define NSTR  16         // stripes per branch (112/7)
#define SCALE 0.20412414523193154f  // 24^-0.5

// ---------------------------------------------------------------------------
// GEMM: Y[M][12544] = W[M][K] @ X[K][12544] + bias[M]
// BM=64, BN=64, BK=32, 256 threads, 4x4 per thread. M,K multiples of 64/32.
// ---------------------------------------------------------------------------
__global__ __launch_bounds__(256) void gemm_bias(
    const float* __restrict__ Wm, const float* __restrict__ bias,
    const float* __restrict__ X, float* __restrict__ Y, const int K) {
  __shared__ float As[32][68];   // [k][m], padded
  __shared__ float Bs[32][64];   // [k][n]
  const int tid = threadIdx.x;
  const int tx = tid & 15, ty = tid >> 4;
  const int bx = blockIdx.x, by = blockIdx.y;
  const int ca = tid & 7, ra = tid >> 3;      // A-staging: 8 float4 per 64-row
  const int cb = tid & 15, rb = tid >> 4;     // B-staging

  float acc[4][4];
#pragma unroll
  for (int i = 0; i < 4; ++i)
#pragma unroll
    for (int j = 0; j < 4; ++j) acc[i][j] = 0.f;

  for (int kk = 0; kk < K; kk += 32) {
    __syncthreads();
#pragma unroll
    for (int p = 0; p < 2; ++p) {
      const int row = ra + p * 32;
      const float4 av = *(const float4*)&Wm[(by * 64 + row) * K + kk + ca * 4];
      As[ca * 4 + 0][row] = av.x;
      As[ca * 4 + 1][row] = av.y;
      As[ca * 4 + 2][row] = av.z;
      As[ca * 4 + 3][row] = av.w;
    }
#pragma unroll
    for (int p = 0; p < 2; ++p) {
      const int row = rb + p * 16;
      *(float4*)&Bs[row][cb * 4] =
          *(const float4*)&X[(kk + row) * HW + bx * 64 + cb * 4];
    }
    __syncthreads();
#pragma unroll
    for (int k = 0; k < 32; ++k) {
      const float4 a = *(const float4*)&As[k][ty * 4];
      const float4 b = *(const float4*)&Bs[k][tx * 4];
      acc[0][0] = fmaf(a.x, b.x, acc[0][0]);
      acc[0][1] = fmaf(a.x, b.y, acc[0][1]);
      acc[0][2] = fmaf(a.x, b.z, acc[0][2]);
      acc[0][3] = fmaf(a.x, b.w, acc[0][3]);
      acc[1][0] = fmaf(a.y, b.x, acc[1][0]);
      acc[1][1] = fmaf(a.y, b.y, acc[1][1]);
      acc[1][2] = fmaf(a.y, b.z, acc[1][2]);
      acc[1][3] = fmaf(a.y, b.w, acc[1][3]);
      acc[2][0] = fmaf(a.z, b.x, acc[2][0]);
      acc[2][1] = fmaf(a.z, b.y, acc[2][1]);
      acc[2][2] = fmaf(a.z, b.z, acc[2][2]);
      acc[2][3] = fmaf(a.z, b.w, acc[2][3]);
      acc[3][0] = fmaf(a.w, b.x, acc[3][0]);
      acc[3][1] = fmaf(a.w, b.y, acc[3][1]);
      acc[3][2] = fmaf(a.w, b.z, acc[3][2]);
      acc[3][3] = fmaf(a.w, b.w, acc[3][3]);
    }
  }
#pragma unroll
  for (int i = 0; i < 4; ++i) {
    const float bi = bias[by * 64 + ty * 4 + i];
    float4 o;
    o.x = acc[i][0] + bi;
    o.y = acc[i][1] + bi;
    o.z = acc[i][2] + bi;
    o.w = acc[i][3] + bi;
    *(float4*)&Y[(by * 64 + ty * 4 + i) * HW + bx * 64 + tx * 4] = o;
  }
}

// ---------------------------------------------------------------------------
// CSWin stripe attention, one (stripe, head, quarter) per block.
// branch 0 = horizontal (token l -> pixel r*784 + l; bias by row offset l/112)
// branch 1 = vertical   (token l = h*7+s -> pixel h*112 + r*7 + s; bias by s=l%7)
// 256 threads; threads 0..195 each own ONE query row (no spill); K/V staged
// in 196-key chunks in LDS (rows padded to 28 floats: 16B-aligned broadcast
// reads, 8-way instead of 16-way staging-write conflicts); 7x7 bias table in
// LDS (no runtime-indexed register arrays -> no scratch).
// ---------------------------------------------------------------------------
__global__ __launch_bounds__(256) void attn_kernel(
    const float* __restrict__ qkv, const float* __restrict__ table,
    float* __restrict__ out, const int branch) {
  const int r = blockIdx.x, head = blockIdx.y, z = blockIdx.z;
  const int tid = threadIdx.x;
  __shared__ float Ks[196][28];
  __shared__ float Vs[196][28];
  __shared__ float b77[49];   // [sl][sm]

  if (tid < 49) {
    const int sl = tid / 7, sm = tid % 7;
    b77[tid] = branch ? table[(6 * 13 + (sl - sm + 6)) * 8 + head]
                      : table[((sl - sm + 6) * 13 + 6) * 8 + head];
  }

  const bool active = tid < 196;
  const int l = z * 196 + tid;           // this thread's query row
  float q[24], a[24];
  float m0 = -1e30f, den = 0.f;
  int pix = 0, slBase = 0;

  if (active) {
    pix = branch ? (l / 7) * Wim + r * 7 + (l % 7) : r * Lr + l;
    slBase = (branch ? (l % 7) : (l / Wim)) * 7;
#pragma unroll
    for (int d = 0; d < 24; ++d) {
      q[d] = qkv[(head * 24 + d) * HW + pix] * SCALE;
      a[d] = 0.f;
    }
  }

  for (int kc = 0; kc < 4; ++kc) {
    __syncthreads();  // protect LDS from previous chunk's readers
    for (int idx = tid; idx < 196 * 24; idx += 256) {
      const int d = idx / 196, m = idx - d * 196;
      const int mg = kc * 196 + m;
      const int p = branch ? (mg / 7) * Wim + r * 7 + (mg % 7) : r * Lr + mg;
      Ks[m][d] = qkv[(Cc + head * 24 + d) * HW + p];
      Vs[m][d] = qkv[(2 * Cc + head * 24 + d) * HW + p];
    }
    __syncthreads();
    if (active) {
      for (int m = 0; m < 196; ++m) {
        const int mg = kc * 196 + m;
        const int sm = branch ? (mg % 7) : (mg / Wim);
        float s = b77[slBase + sm];
#pragma unroll
        for (int d = 0; d < 24; ++d) s = fmaf(q[d], Ks[m][d], s);
        if (s > m0) {  // deferred rescale (rare after warm-up)
          const float cf = __expf(m0 - s);
          m0 = s;
          den *= cf;
#pragma unroll
          for (int d = 0; d < 24; ++d) a[d] *= cf;
        }
        const float p = __expf(s - m0);
        den += p;
#pragma unroll
        for (int d = 0; d < 24; ++d) a[d] = fmaf(p, Vs[m][d], a[d]);
      }
    }
  }

  if (active) {
    const float inv = 1.f / den;
#pragma unroll
    for (int d = 0; d < 24; ++d)
      out[(head * 24 + d) * HW + pix] = a[d] * inv;
  }
}

// ---------------------------------------------------------------------------
// LePE (depthwise 3x3 + bias -> exact GELU -> residual) for both branches,
// then t = 0.5*(lepe_h + lepe_v)
// ---------------------------------------------------------------------------
__device__ __forceinline__ float gelu_exact(float x) {
  return 0.5f * x * (1.f + erff(x * 0.7071067811865476f));
}

__global__ __launch_bounds__(256) void lepe_combine(
    const float* __restrict__ oh, const float* __restrict__ ov,
    const float* __restrict__ wh, const float* __restrict__ bh,
    const float* __restrict__ wv, const float* __restrict__ bv,
    float* __restrict__ t) {
  const int idx = blockIdx.x * 256 + threadIdx.x;
  if (idx >= Cc * HW) return;
  const int c = idx / HW, pos = idx - c * HW;
  const int h = pos / Wim, w = pos - (pos / Wim) * Wim;
  float sh = 0.f, sv = 0.f;
#pragma unroll
  for (int ky = 0; ky < 3; ++ky) {
    const int hh = h + ky - 1;
    if (hh < 0 || hh >= Him) continue;
#pragma unroll
    for (int kx = 0; kx < 3; ++kx) {
      const int wwp = w + kx - 1;
      if (wwp < 0 || wwp >= Wim) continue;
      const int p = c * HW + hh * Wim + wwp;
      const float wt_h = wh[c * 9 + ky * 3 + kx];
      const float wt_v = wv[c * 9 + ky * 3 + kx];
      sh = fmaf(oh[p], wt_h, sh);
      sv = fmaf(ov[p], wt_v, sv);
    }
  }
  const float rh = oh[idx] + gelu_exact(sh + bh[c]);
  const float rv = ov[idx] + gelu_exact(sv + bv[c]);
  t[idx] = 0.5f * (rh + rv);
}

// ---------------------------------------------------------------------------
// Launch: qkv_h GEMM -> attn_h -> qkv_v GEMM (reuse buffer) -> attn_v
//         -> lepe+combine -> proj GEMM.
// ---------------------------------------------------------------------------
extern "C" void kernel_launch(void* const* d_in, const int* in_sizes, int n_in,
                              void* d_out, int out_size, void* d_ws,
                              size_t ws_size, hipStream_t stream) {
  const float* x        = (const float*)d_in[0];
  const float* qkv_h_w  = (const float*)d_in[1];
  const float* qkv_h_b  = (const float*)d_in[2];
  const float* qkv_v_w  = (const float*)d_in[3];
  const float* qkv_v_b  = (const float*)d_in[4];
  const float* proj_w   = (const float*)d_in[5];
  const float* proj_b   = (const float*)d_in[6];
  const float* lepe_h_w = (const float*)d_in[7];
  const float* lepe_h_b = (const float*)d_in[8];
  const float* lepe_v_w = (const float*)d_in[9];
  const float* lepe_v_b = (const float*)d_in[10];
  const float* table_h  = (const float*)d_in[11];
  const float* table_v  = (const float*)d_in[12];
  float* outp = (float*)d_out;

  float* ws    = (float*)d_ws;
  float* qkvb  = ws;                       // 576*HW floats
  float* out_h = qkvb + 3 * Cc * HW;       // 192*HW
  float* out_v = out_h + Cc * HW;          // 192*HW
  float* tbuf  = out_v + Cc * HW;          // 192*HW

  const dim3 blk(256);
  // horizontal branch
  gemm_bias<<<dim3(HW / 64, (3 * Cc) / 64), blk, 0, stream>>>(qkv_h_w, qkv_h_b,
                                                              x, qkvb, Cc);
  attn_kernel<<<dim3(NSTR, NH, 4), blk, 0, stream>>>(qkvb, table_h, out_h, 0);
  // vertical branch (reuses qkv buffer)
  gemm_bias<<<dim3(HW / 64, (3 * Cc) / 64), blk, 0, stream>>>(qkv_v_w, qkv_v_b,
                                                              x, qkvb, Cc);
  attn_kernel<<<dim3(NSTR, NH, 4), blk, 0, stream>>>(qkvb, table_v, out_v, 1);
  // lepe + combine
  lepe_combine<<<dim3((Cc * HW + 255) / 256), blk, 0, stream>>>(
      out_h, out_v, lepe_h_w, lepe_h_b, lepe_v_w, lepe_v_b, tbuf);
  // projection
  gemm_bias<<<dim3(HW / 64, Cc / 64), blk, 0, stream>>>(proj_w, proj_b, tbuf,
                                                        outp, Cc);
}

// Round 8
// 478.371 us; speedup vs baseline: 1.9840x; 1.4257x over previous
//
#include <hip/hip_runtime.h>
#include <math.h>

// Problem constants
#define Cc    192
#define NH    8
#define HD    24
#define Him   112
#define Wim   112
#define HW    12544      // 112*112
#define Lr    784        // tokens per stripe window (7*112)
#define NSTR  16         // stripes per branch (112/7)
#define SCALE 0.20412414523193154f  // 24^-0.5

typedef __attribute__((ext_vector_type(4))) float f32x4;
typedef __attribute__((ext_vector_type(8))) short bf16x8;
typedef __attribute__((ext_vector_type(2))) unsigned int u32x2;
typedef __attribute__((ext_vector_type(4))) unsigned int u32x4;

union B8 { u32x4 u; bf16x8 h; };

__device__ __forceinline__ unsigned pk2(float a, float b) {
  union { float f; unsigned u; } x, y;
  x.f = a; y.f = b;
  unsigned ra = x.u + 0x7FFFu + ((x.u >> 16) & 1u);
  unsigned rb = y.u + 0x7FFFu + ((y.u >> 16) & 1u);
  return (ra >> 16) | (rb & 0xFFFF0000u);
}

__device__ __forceinline__ u32x2 tr8(unsigned addr) {
  u32x2 t;
  asm volatile("ds_read_b64_tr_b16 %0, %1" : "=v"(t) : "v"(addr));
  return t;
}
__device__ __forceinline__ void lgkm0() {
  asm volatile("s_waitcnt lgkmcnt(0)" ::: "memory");
  __builtin_amdgcn_sched_barrier(0);
}
__device__ __forceinline__ float sel4(float a0, float a1, float a2, float a3, int s) {
  return s == 0 ? a0 : s == 1 ? a1 : s == 2 ? a2 : a3;
}

// ---------------------------------------------------------------------------
// MFMA flash attention. One block = (stripe r, head h, 8 query-frags of 16).
// branch 0 = horizontal: q-frag f covers tokens f*16..f*16+15 (bias row f/7,
//            uniform per chunk = key row c). branch 1 = vertical: frag f ->
//            s=f%7, i=f/7, tokens q = s + 7*(i*16+qrow) (bias from s, key%7).
// Keys chunked 112 (7 kb of 16). K staged sigma-permuted [7][32][16] bf16 for
// ds_read_b64_tr_b16 B-frags; V staged as V^T [32][132] bf16 (cols 112..127
// and rows 24..31 zeroed pad). P^T written bf16 to per-wave [128][16] region
// (sigma-permuted rows; pad-key rows {104..111,120..127} zeroed) and tr-read
// back as the PV B-operand: O^T = V^T * P^T. Softmax fp32 in C-layout regs;
// row-sum AND row-max both reduced across the 16-lane column group.
// ---------------------------------------------------------------------------
template <int BR>
__global__ __launch_bounds__(256, 3) void attn_mfma(
    const float* __restrict__ qkv, const float* __restrict__ table,
    float* __restrict__ out) {
  const int r = blockIdx.x, h = blockIdx.y, z = blockIdx.z;
  const int tid = threadIdx.x;
  const int w = tid >> 6, lane = tid & 63, g = lane >> 4, col = lane & 15;

  __shared__ __align__(128) unsigned short Ks[7][32][16];   // 7168 B
  __shared__ __align__(128) unsigned short Vt[32][132];     // 8448 B
  __shared__ __align__(128) unsigned short Pt[4][128][16];  // 16384 B
  __shared__ float blv[13];

  // --- one-time zeroing ---
  // K pad rows (mfma-k d=24..31 -> rho {12..15, 28..31}) per kb tile
  for (int u = tid; u < 448; u += 256) {
    int kb = u >> 6, j = u & 63, rr = j >> 3;
    int row = (rr < 4) ? (12 + rr) : (24 + rr);
    *(unsigned*)&Ks[kb][row][(j & 7) * 2] = 0u;
  }
  // Pt pad rows: keys 112..127 (kab=7) -> rho rows {104..111, 120..127}
  for (int u = tid; u < 512; u += 256) {
    int ww = u >> 7, j = u & 127, rr = j >> 3;
    int row = (rr < 8) ? (104 + rr) : (112 + rr);
    *(unsigned*)&Pt[ww][row][(j & 7) * 2] = 0u;
  }
  // Vt pad cols 112..127, rows 0..31
  for (int u = tid; u < 256; u += 256) {
    int row = u >> 3;
    *(unsigned*)&Vt[row][112 + (u & 7) * 2] = 0u;
  }
  // Vt pad rows 24..31 (read by PV A-operand, never written by staging)
  for (int u = tid; u < 528; u += 256) {
    int row = 24 + u / 66, cp = u % 66;
    *(unsigned*)&Vt[row][cp * 2] = 0u;
  }
  if (tid < 13)
    blv[tid] = (BR == 0) ? table[(tid * 13 + 6) * 8 + h]
                         : table[(6 * 13 + tid) * 8 + h];

  // --- frag setup (2 frags per wave) ---
  const int f0 = z * 8 + w * 2, f1 = f0 + 1;
  const bool vA = (f0 < 49), vB = (f1 < 49);
  const int fA = vA ? f0 : 48, fB = vB ? f1 : 48;

  int pixA, pixB, slA, slB;
  if (BR == 0) {
    pixA = r * Lr + fA * 16 + col;
    pixB = r * Lr + fB * 16 + col;
    slA = fA / 7; slB = fB / 7;
  } else {
    slA = fA % 7; slB = fB % 7;
    pixA = ((fA / 7) * 16 + col) * Wim + r * 7 + slA;
    pixB = ((fB / 7) * 16 + col) * Wim + r * 7 + slB;
  }

  // Q fragments (A-operand: row q = col, k-elems d = g*8+0..7, pad d>=24 -> 0)
  B8 QA, QB;
  {
    unsigned qa[4], qb[4];
#pragma unroll
    for (int jj = 0; jj < 4; ++jj) {
      int d0 = g * 8 + jj * 2, d1 = d0 + 1;
      float a0 = 0.f, a1 = 0.f, b0 = 0.f, b1 = 0.f;
      if (g < 3) {
        a0 = qkv[(h * 24 + d0) * HW + pixA] * SCALE;
        a1 = qkv[(h * 24 + d1) * HW + pixA] * SCALE;
        b0 = qkv[(h * 24 + d0) * HW + pixB] * SCALE;
        b1 = qkv[(h * 24 + d1) * HW + pixB] * SCALE;
      }
      qa[jj] = pk2(a0, a1);
      qb[jj] = pk2(b0, b1);
    }
    QA.u = (u32x4){qa[0], qa[1], qa[2], qa[3]};
    QB.u = (u32x4){qb[0], qb[1], qb[2], qb[3]};
  }
  __syncthreads();  // blv + zero regions visible

  // vertical bias registers: bias(frag, kb) lane-varying, chunk-invariant
  float bvA[7], bvB[7];
  if (BR == 1) {
    int cm7 = col % 7;
#pragma unroll
    for (int kb = 0; kb < 7; ++kb) {
      int t = cm7 + 2 * kb;
      t -= (t >= 7) ? 7 : 0;
      t -= (t >= 7) ? 7 : 0;
      bvA[kb] = blv[slA - t + 6];
      bvB[kb] = blv[slB - t + 6];
    }
  }

  f32x4 OA0 = {0,0,0,0}, OA1 = {0,0,0,0}, OB0 = {0,0,0,0}, OB1 = {0,0,0,0};
  float mA[4], mB[4], dnA[4], dnB[4];
#pragma unroll
  for (int i = 0; i < 4; ++i) { mA[i] = -1e30f; mB[i] = -1e30f; dnA[i] = 0.f; dnB[i] = 0.f; }

  const unsigned kTr = (unsigned)(size_t)(&Ks[0][0][0]) + lane * 8;
  const unsigned pTr = (unsigned)(size_t)(&Pt[w][0][0]) + lane * 8;
  const int srcl = (col >> 2) << 4;  // source lane for reg->col redistribution
  const int c3 = col & 3;

// --- softmax + P-write + PV for one frag ---
#define FRAGP(S_, m_, dn_, O0_, O1_, KB0, NKB, KS0)                          \
  {                                                                          \
    float cf[4];                                                             \
    _Pragma("unroll") for (int q = 0; q < 4; ++q) {                          \
      float mm = S_[0][q];                                                   \
      _Pragma("unroll") for (int kb = 1; kb < NKB; ++kb)                     \
          mm = fmaxf(mm, S_[kb][q]);                                         \
      mm = fmaxf(mm, __shfl_xor(mm, 1));                                     \
      mm = fmaxf(mm, __shfl_xor(mm, 2));                                     \
      mm = fmaxf(mm, __shfl_xor(mm, 4));                                     \
      mm = fmaxf(mm, __shfl_xor(mm, 8));                                     \
      float mn = fmaxf(m_[q], mm);                                           \
      cf[q] = __expf(m_[q] - mn);                                            \
      m_[q] = mn;                                                            \
      float ps = 0.f;                                                        \
      _Pragma("unroll") for (int kb = 0; kb < NKB; ++kb) {                   \
        float p = __expf(S_[kb][q] - mn);                                    \
        S_[kb][q] = p; ps += p;                                              \
      }                                                                      \
      ps += __shfl_xor(ps, 1);                                               \
      ps += __shfl_xor(ps, 2);                                               \
      ps += __shfl_xor(ps, 4);                                               \
      ps += __shfl_xor(ps, 8);                                               \
      dn_[q] = dn_[q] * cf[q] + ps;                                          \
    }                                                                        \
    float cc0 = __shfl(cf[0], srcl), cc1 = __shfl(cf[1], srcl);              \
    float cc2 = __shfl(cf[2], srcl), cc3 = __shfl(cf[3], srcl);              \
    float cfc = sel4(cc0, cc1, cc2, cc3, c3);                                \
    _Pragma("unroll") for (int q = 0; q < 4; ++q) { O0_[q] *= cfc; O1_[q] *= cfc; } \
    _Pragma("unroll") for (int kb = 0; kb < NKB; ++kb) {                     \
      const int kab = KB0 + kb;                                              \
      int rho = ((kab >> 1) << 5) + (((col >> 2) & 1) << 4) +                \
                ((((kab & 1) << 1) + (col >> 3)) << 2) + (col & 3);          \
      uint2 pw;                                                              \
      pw.x = pk2(S_[kb][0], S_[kb][1]);                                      \
      pw.y = pk2(S_[kb][2], S_[kb][3]);                                      \
      *(uint2*)&Pt[w][rho][g * 4] = pw;                                      \
    }                                                                        \
    lgkm0();                                                                 \
    _Pragma("unroll") for (int ks = 0; ks < 2; ++ks) {                       \
      u32x2 p1 = tr8(pTr + (KS0 + ks) * 1024);                               \
      u32x2 p2 = tr8(pTr + (KS0 + ks) * 1024 + 512);                         \
      uint2 va0 = *(const uint2*)&Vt[col][(KS0 + ks) * 32 + g * 8];          \
      uint2 va1 = *(const uint2*)&Vt[col][(KS0 + ks) * 32 + g * 8 + 4];      \
      uint2 vb0 = *(const uint2*)&Vt[16 + col][(KS0 + ks) * 32 + g * 8];     \
      uint2 vb1 = *(const uint2*)&Vt[16 + col][(KS0 + ks) * 32 + g * 8 + 4]; \
      lgkm0();                                                               \
      B8 Bf; Bf.u = (u32x4){p1.x, p1.y, p2.x, p2.y};                         \
      B8 V0; V0.u = (u32x4){va0.x, va0.y, va1.x, va1.y};                     \
      B8 V1; V1.u = (u32x4){vb0.x, vb0.y, vb1.x, vb1.y};                     \
      O0_ = __builtin_amdgcn_mfma_f32_16x16x32_bf16(V0.h, Bf.h, O0_, 0, 0, 0); \
      O1_ = __builtin_amdgcn_mfma_f32_16x16x32_bf16(V1.h, Bf.h, O1_, 0, 0, 0); \
    }                                                                        \
  }

#define ROUND(KB0, NKB, KS0)                                                 \
  {                                                                          \
    u32x2 kt[NKB][2];                                                        \
    _Pragma("unroll") for (int kb = 0; kb < NKB; ++kb) {                     \
      kt[kb][0] = tr8(kTr + (KB0 + kb) * 1024);                              \
      kt[kb][1] = tr8(kTr + (KB0 + kb) * 1024 + 512);                        \
    }                                                                        \
    lgkm0();                                                                 \
    f32x4 SA[NKB], SB[NKB];                                                  \
    _Pragma("unroll") for (int kb = 0; kb < NKB; ++kb) {                     \
      B8 Kf;                                                                 \
      Kf.u = (u32x4){kt[kb][0].x, kt[kb][0].y, kt[kb][1].x, kt[kb][1].y};    \
      f32x4 zz = {0.f, 0.f, 0.f, 0.f};                                       \
      SA[kb] = __builtin_amdgcn_mfma_f32_16x16x32_bf16(QA.h, Kf.h, zz, 0, 0, 0); \
      SB[kb] = __builtin_amdgcn_mfma_f32_16x16x32_bf16(QB.h, Kf.h, zz, 0, 0, 0); \
      float ba = (BR == 0) ? bcA : bvA[KB0 + kb];                            \
      float bb = (BR == 0) ? bcB : bvB[KB0 + kb];                            \
      _Pragma("unroll") for (int q = 0; q < 4; ++q) {                        \
        SA[kb][q] += ba; SB[kb][q] += bb;                                    \
      }                                                                      \
    }                                                                        \
    FRAGP(SA, mA, dnA, OA0, OA1, KB0, NKB, KS0)                              \
    FRAGP(SB, mB, dnB, OB0, OB1, KB0, NKB, KS0)                              \
  }

  for (int c = 0; c < 7; ++c) {
    float bcA = 0.f, bcB = 0.f;
    if (BR == 0) {  // horizontal bias: uniform scalar per (frag, chunk)
      bcA = table[((slA - c + 6) * 13 + 6) * 8 + h];
      bcB = table[((slB - c + 6) * 13 + 6) * 8 + h];
    }
    __syncthreads();  // previous chunk's LDS reads complete
    // --- stage K (sigma-permuted) and V^T, fp32 -> bf16 ---
    const int cb = c * 112;
    for (int u = tid; u < 1344; u += 256) {
      int c0 = u & 7, rest = u >> 3;
      int d = rest % 24, kh = rest / 24;
      int k = (kh * 8 + c0) * 2;
      float k0, k1, v0, v1;
      if (BR == 0) {
        float2 kk = *(const float2*)&qkv[(Cc + h * 24 + d) * HW + r * Lr + cb + k];
        float2 vv = *(const float2*)&qkv[(2 * Cc + h * 24 + d) * HW + r * Lr + cb + k];
        k0 = kk.x; k1 = kk.y; v0 = vv.x; v1 = vv.y;
      } else {
        int m0i = cb + k, m1i = m0i + 1;
        int p0 = (m0i / 7) * Wim + r * 7 + (m0i % 7);
        int p1 = (m1i / 7) * Wim + r * 7 + (m1i % 7);
        k0 = qkv[(Cc + h * 24 + d) * HW + p0];
        k1 = qkv[(Cc + h * 24 + d) * HW + p1];
        v0 = qkv[(2 * Cc + h * 24 + d) * HW + p0];
        v1 = qkv[(2 * Cc + h * 24 + d) * HW + p1];
      }
      int kb = k >> 4, kc = k & 15;
      int rho = (d >> 3) * 4 + (d & 3) + (((d >> 2) & 1) << 4);
      *(unsigned*)&Ks[kb][rho][kc] = pk2(k0, k1);
      *(unsigned*)&Vt[d][k] = pk2(v0, v1);
    }
    __syncthreads();

    ROUND(0, 4, 0)   // kb 0..3, P rows 0..63,   PV key-steps 0..1
    ROUND(4, 3, 2)   // kb 4..6, P rows 64..127, PV key-steps 2..3 (pads zero)
  }

  // --- epilogue: normalize and store O^T (row d, col q) ---
  {
    float d0 = __shfl(dnA[0], srcl), d1 = __shfl(dnA[1], srcl);
    float d2 = __shfl(dnA[2], srcl), d3 = __shfl(dnA[3], srcl);
    float inv = 1.f / sel4(d0, d1, d2, d3, c3);
    if (vA) {
#pragma unroll
      for (int q = 0; q < 4; ++q) {
        int dd = g * 4 + q;
        out[(h * 24 + dd) * HW + pixA] = OA0[q] * inv;
        if (g < 2) out[(h * 24 + 16 + dd) * HW + pixA] = OA1[q] * inv;
      }
    }
  }
  {
    float d0 = __shfl(dnB[0], srcl), d1 = __shfl(dnB[1], srcl);
    float d2 = __shfl(dnB[2], srcl), d3 = __shfl(dnB[3], srcl);
    float inv = 1.f / sel4(d0, d1, d2, d3, c3);
    if (vB) {
#pragma unroll
      for (int q = 0; q < 4; ++q) {
        int dd = g * 4 + q;
        out[(h * 24 + dd) * HW + pixB] = OB0[q] * inv;
        if (g < 2) out[(h * 24 + 16 + dd) * HW + pixB] = OB1[q] * inv;
      }
    }
  }
#undef FRAGP
#undef ROUND
}

// ---------------------------------------------------------------------------
// GEMM: Y[M][12544] = W[M][K] @ X[K][12544] + bias[M]  (fp32 vector path)
// ---------------------------------------------------------------------------
__global__ __launch_bounds__(256) void gemm_bias(
    const float* __restrict__ Wm, const float* __restrict__ bias,
    const float* __restrict__ X, float* __restrict__ Y, const int K) {
  __shared__ float As[32][68];
  __shared__ float Bs[32][64];
  const int tid = threadIdx.x;
  const int tx = tid & 15, ty = tid >> 4;
  const int bx = blockIdx.x, by = blockIdx.y;
  const int ca = tid & 7, ra = tid >> 3;
  const int cbi = tid & 15, rb = tid >> 4;

  float acc[4][4];
#pragma unroll
  for (int i = 0; i < 4; ++i)
#pragma unroll
    for (int j = 0; j < 4; ++j) acc[i][j] = 0.f;

  for (int kk = 0; kk < K; kk += 32) {
    __syncthreads();
#pragma unroll
    for (int p = 0; p < 2; ++p) {
      const int row = ra + p * 32;
      const float4 av = *(const float4*)&Wm[(by * 64 + row) * K + kk + ca * 4];
      As[ca * 4 + 0][row] = av.x;
      As[ca * 4 + 1][row] = av.y;
      As[ca * 4 + 2][row] = av.z;
      As[ca * 4 + 3][row] = av.w;
    }
#pragma unroll
    for (int p = 0; p < 2; ++p) {
      const int row = rb + p * 16;
      *(float4*)&Bs[row][cbi * 4] =
          *(const float4*)&X[(kk + row) * HW + bx * 64 + cbi * 4];
    }
    __syncthreads();
#pragma unroll
    for (int k = 0; k < 32; ++k) {
      const float4 a = *(const float4*)&As[k][ty * 4];
      const float4 b = *(const float4*)&Bs[k][tx * 4];
      acc[0][0] = fmaf(a.x, b.x, acc[0][0]);
      acc[0][1] = fmaf(a.x, b.y, acc[0][1]);
      acc[0][2] = fmaf(a.x, b.z, acc[0][2]);
      acc[0][3] = fmaf(a.x, b.w, acc[0][3]);
      acc[1][0] = fmaf(a.y, b.x, acc[1][0]);
      acc[1][1] = fmaf(a.y, b.y, acc[1][1]);
      acc[1][2] = fmaf(a.y, b.z, acc[1][2]);
      acc[1][3] = fmaf(a.y, b.w, acc[1][3]);
      acc[2][0] = fmaf(a.z, b.x, acc[2][0]);
      acc[2][1] = fmaf(a.z, b.y, acc[2][1]);
      acc[2][2] = fmaf(a.z, b.z, acc[2][2]);
      acc[2][3] = fmaf(a.z, b.w, acc[2][3]);
      acc[3][0] = fmaf(a.w, b.x, acc[3][0]);
      acc[3][1] = fmaf(a.w, b.y, acc[3][1]);
      acc[3][2] = fmaf(a.w, b.z, acc[3][2]);
      acc[3][3] = fmaf(a.w, b.w, acc[3][3]);
    }
  }
#pragma unroll
  for (int i = 0; i < 4; ++i) {
    const float bi = bias[by * 64 + ty * 4 + i];
    float4 o;
    o.x = acc[i][0] + bi;
    o.y = acc[i][1] + bi;
    o.z = acc[i][2] + bi;
    o.w = acc[i][3] + bi;
    *(float4*)&Y[(by * 64 + ty * 4 + i) * HW + bx * 64 + tx * 4] = o;
  }
}

// ---------------------------------------------------------------------------
// LePE (depthwise 3x3 + bias -> exact GELU -> residual) x2 branches, combine.
// ---------------------------------------------------------------------------
__device__ __forceinline__ float gelu_exact(float x) {
  return 0.5f * x * (1.f + erff(x * 0.7071067811865476f));
}

__global__ __launch_bounds__(256) void lepe_combine(
    const float* __restrict__ oh, const float* __restrict__ ov,
    const float* __restrict__ wh, const float* __restrict__ bh,
    const float* __restrict__ wv, const float* __restrict__ bv,
    float* __restrict__ t) {
  const int idx = blockIdx.x * 256 + threadIdx.x;
  if (idx >= Cc * HW) return;
  const int c = idx / HW, pos = idx - c * HW;
  const int h = pos / Wim, w = pos - (pos / Wim) * Wim;
  float sh = 0.f, sv = 0.f;
#pragma unroll
  for (int ky = 0; ky < 3; ++ky) {
    const int hh = h + ky - 1;
    if (hh < 0 || hh >= Him) continue;
#pragma unroll
    for (int kx = 0; kx < 3; ++kx) {
      const int wwp = w + kx - 1;
      if (wwp < 0 || wwp >= Wim) continue;
      const int p = c * HW + hh * Wim + wwp;
      sh = fmaf(oh[p], wh[c * 9 + ky * 3 + kx], sh);
      sv = fmaf(ov[p], wv[c * 9 + ky * 3 + kx], sv);
    }
  }
  const float rh = oh[idx] + gelu_exact(sh + bh[c]);
  const float rv = ov[idx] + gelu_exact(sv + bv[c]);
  t[idx] = 0.5f * (rh + rv);
}

// ---------------------------------------------------------------------------
extern "C" void kernel_launch(void* const* d_in, const int* in_sizes, int n_in,
                              void* d_out, int out_size, void* d_ws,
                              size_t ws_size, hipStream_t stream) {
  const float* x        = (const float*)d_in[0];
  const float* qkv_h_w  = (const float*)d_in[1];
  const float* qkv_h_b  = (const float*)d_in[2];
  const float* qkv_v_w  = (const float*)d_in[3];
  const float* qkv_v_b  = (const float*)d_in[4];
  const float* proj_w   = (const float*)d_in[5];
  const float* proj_b   = (const float*)d_in[6];
  const float* lepe_h_w = (const float*)d_in[7];
  const float* lepe_h_b = (const float*)d_in[8];
  const float* lepe_v_w = (const float*)d_in[9];
  const float* lepe_v_b = (const float*)d_in[10];
  const float* table_h  = (const float*)d_in[11];
  const float* table_v  = (const float*)d_in[12];
  float* outp = (float*)d_out;

  float* ws    = (float*)d_ws;
  float* qkvb  = ws;                       // 576*HW floats
  float* out_h = qkvb + 3 * Cc * HW;       // 192*HW
  float* out_v = out_h + Cc * HW;          // 192*HW
  float* tbuf  = out_v + Cc * HW;          // 192*HW

  const dim3 blk(256);
  // horizontal branch
  gemm_bias<<<dim3(HW / 64, (3 * Cc) / 64), blk, 0, stream>>>(qkv_h_w, qkv_h_b,
                                                              x, qkvb, Cc);
  attn_mfma<0><<<dim3(NSTR, NH, 7), blk, 0, stream>>>(qkvb, table_h, out_h);
  // vertical branch (reuses qkv buffer)
  gemm_bias<<<dim3(HW / 64, (3 * Cc) / 64), blk, 0, stream>>>(qkv_v_w, qkv_v_b,
                                                              x, qkvb, Cc);
  attn_mfma<1><<<dim3(NSTR, NH, 7), blk, 0, stream>>>(qkvb, table_v, out_v);
  // lepe + combine
  lepe_combine<<<dim3((Cc * HW + 255) / 256), blk, 0, stream>>>(
      out_h, out_v, lepe_h_w, lepe_h_b, lepe_v_w, lepe_v_b, tbuf);
  // projection
  gemm_bias<<<dim3(HW / 64, Cc / 64), blk, 0, stream>>>(proj_w, proj_b, tbuf,
                                                        outp, Cc);
}